// Round 4
// baseline (329.807 us; speedup 1.0000x reference)
//
#include <hip/hip_runtime.h>

typedef short short8 __attribute__((ext_vector_type(8)));
typedef float floatx4 __attribute__((ext_vector_type(4)));

#define TDIM 6
#define XDIM 24
#define YDIM 24
#define ZDIM 12
#define VOL 41472   // 6*24*24*12
#define EPSV 1e-5f
#define SLOPE 0.1f

// Padded act layout (stride = CIN): pv(t,x,y,z) = ((t*24+x)*28 + y+2)*16 + z+2
// elem = pv*CIN + c.  Halo (py 0,1,26,27 / pz 0,1,14,15) stays zero.
// workspace byte offsets
#define ACT16_B   256u        // guard 256B before; data 64512*16*2 = 2,064,384
#define ACT32_B   2064896u    // guard gap before; data 64512*32*2 = 4,128,768
#define CONVB_B   6193664u    // bf16 conv out: VOL*32*2 = 2,654,208
#define WB_B      8847872u    // B-frags: up to 768,000
#define PART_B    9615872u    // 576*32*2*4 = 147,456
#define STATS_B   9763328u    // 512
#define ZERO_BLKS 1513        // zero [0, ~6.19MB) in 4KB blocks

__device__ inline unsigned short f2bf(float f) {
  unsigned u = __builtin_bit_cast(unsigned, f);
  unsigned r = u + 0x7fffu + ((u >> 16) & 1u);
  return (unsigned short)(r >> 16);
}
__device__ inline float bf2f(unsigned short h) {
  unsigned u = ((unsigned)h) << 16;
  return __builtin_bit_cast(float, u);
}

__global__ __launch_bounds__(256) void zero_act(float4* __restrict__ p) {
  p[blockIdx.x * 256 + threadIdx.x] = make_float4(0.f, 0.f, 0.f, 0.f);
}

// ---------------- embed -> ACT16 (stride 16) ------------------------------
__global__ __launch_bounds__(256) void embed_kernel(
    const float* __restrict__ x, const float* __restrict__ w,
    const float* __restrict__ b, unsigned short* __restrict__ act) {
  int v = blockIdx.x * 256 + threadIdx.x;
  const float4* xp = reinterpret_cast<const float4*>(x + (size_t)v * 8);
  float4 x0 = xp[0], x1 = xp[1];
  float xv[8] = {x0.x, x0.y, x0.z, x0.w, x1.x, x1.y, x1.z, x1.w};
  float acc[16];
  #pragma unroll
  for (int h = 0; h < 16; ++h) acc[h] = b[h];
  #pragma unroll
  for (int f = 0; f < 8; ++f)
    #pragma unroll
    for (int h = 0; h < 16; ++h)
      acc[h] = fmaf(xv[f], w[f * 16 + h], acc[h]);
  int z = v % 12, y = (v / 12) % 24, xx = (v / 288) % 24, t = v / 6912;
  size_t pa = ((size_t)((t * 24 + xx) * 28 + y + 2) * 16 + z + 2) * 16;
  short8 o0, o1;
  #pragma unroll
  for (int h = 0; h < 8; ++h) { o0[h] = (short)f2bf(acc[h]); o1[h] = (short)f2bf(acc[8 + h]); }
  short8* op = reinterpret_cast<short8*>(act + pa);
  op[0] = o0; op[1] = o1;
}

// ---------------- weight -> B-fragment-ordered bf16 -----------------------
// wb[((q*NP + p)*NCOG + cog)*64 + lane], q=(dt*5+dx)*5+dy
// CIN16: k=g*8+j -> dz=2p+(g>>1), ci=(g&1)*8+j ; CIN32: ci=g*8+j, dz=p
template<int CIN, int COUT>
__global__ __launch_bounds__(256) void wtrans_mfma(
    const float* __restrict__ w, short8* __restrict__ wb) {
  constexpr int NP = (CIN == 16) ? 3 : 5;
  constexpr int NCOG = COUT / 16;
  int id = blockIdx.x * 256 + threadIdx.x;
  if (id >= 125 * NP * NCOG * 64) return;
  int lane = id & 63;
  int q = id >> 6;
  int cog = q % NCOG; q /= NCOG;
  int p = q % NP; q /= NP;            // q = (dt*5+dx)*5+dy
  int g = lane >> 4, n = lane & 15;
  int co = cog * 16 + n;
  short8 out;
  #pragma unroll
  for (int j = 0; j < 8; ++j) {
    int ci = (CIN == 16) ? ((g & 1) * 8 + j) : (g * 8 + j);
    int dz = (CIN == 16) ? (2 * p + (g >> 1)) : p;
    float val = 0.f;
    if (dz < 5) val = w[((size_t)co * CIN + ci) * 625 + q * 5 + dz];
    out[j] = (short)f2bf(val);
  }
  wb[id] = out;
}

// ---------------- conv4d MFMA v4: pz-Mtile, register-blocked --------------
// Block = (t, x, yq): 6*24*4 = 576 blocks, 128 thr = 2 waves.
// Wave owns 3 y-rows (y0 = yq*6 + w*3); M-rows of MFMA = pz 0..15 (z -2..13).
// Epilogue: bf16 conv store + per-block BN partial sums (fused bn_stats1).
template<int CIN, int COUT>
__global__ __launch_bounds__(128, 2) void conv4d_v4(
    const unsigned short* __restrict__ act, const short8* __restrict__ wb,
    const float* __restrict__ bias, unsigned short* __restrict__ convout,
    float* __restrict__ part) {
  constexpr int NP = (CIN == 16) ? 3 : 5;
  constexpr int NCOG = COUT / 16;
  constexpr int RS = 16 * CIN;              // elements per py row
  const int tid = threadIdx.x;
  const int l = tid & 63;
  const int w = tid >> 6;                   // wave 0..1
  const int col = l & 15, g = l >> 4;
  const int bid = blockIdx.x;
  const int yq = bid & 3;
  const int x = (bid >> 2) % 24;
  const int t = bid / 96;
  const int y0 = yq * 6 + w * 3;
  const int laneoff0 = (CIN == 16) ? ((col + (g >> 1) - 2) * 16 + (g & 1) * 8)
                                   : ((col - 2) * 32 + g * 8);

  floatx4 acc[3][NCOG];
  #pragma unroll
  for (int m = 0; m < 3; ++m)
    #pragma unroll
    for (int cg = 0; cg < NCOG; ++cg) acc[m][cg] = (floatx4){0.f, 0.f, 0.f, 0.f};

  for (int dt = 0; dt < 5; ++dt) {
    int ti = t + dt - 2;
    if ((unsigned)ti >= (unsigned)TDIM) continue;      // block-uniform
    for (int dx = 0; dx < 5; ++dx) {
      int xi = x + dx - 2;
      if ((unsigned)xi >= (unsigned)XDIM) continue;    // block-uniform
      const int ebase = (((ti * 24 + xi) * 28 + y0) * 16) * CIN + laneoff0;
      const short8* bp = wb + (size_t)((dt * 5 + dx) * 5 * NP) * NCOG * 64 + l;
      if constexpr (CIN == 16) {
        short8 A[7][3];
        #pragma unroll
        for (int r = 0; r < 7; ++r)
          #pragma unroll
          for (int p = 0; p < 3; ++p)
            A[r][p] = *reinterpret_cast<const short8*>(act + ebase + r * RS + p * 32);
        #pragma unroll
        for (int dy = 0; dy < 5; ++dy) {
          short8 Bf[3][NCOG];
          #pragma unroll
          for (int p = 0; p < 3; ++p)
            #pragma unroll
            for (int cg = 0; cg < NCOG; ++cg)
              Bf[p][cg] = bp[((dy * 3 + p) * NCOG + cg) * 64];
          #pragma unroll
          for (int p = 0; p < 3; ++p)
            #pragma unroll
            for (int cg = 0; cg < NCOG; ++cg)
              #pragma unroll
              for (int m = 0; m < 3; ++m)
                acc[m][cg] = __builtin_amdgcn_mfma_f32_16x16x32_bf16(
                    A[m + dy][p], Bf[p][cg], acc[m][cg], 0, 0, 0);
        }
      } else {
        #pragma unroll
        for (int dy = 0; dy < 5; ++dy) {
          short8 A[3][5];
          #pragma unroll
          for (int m = 0; m < 3; ++m)
            #pragma unroll
            for (int p = 0; p < 5; ++p)
              A[m][p] = *reinterpret_cast<const short8*>(act + ebase + (m + dy) * RS + p * 32);
          short8 Bf[5][NCOG];
          #pragma unroll
          for (int p = 0; p < 5; ++p)
            #pragma unroll
            for (int cg = 0; cg < NCOG; ++cg)
              Bf[p][cg] = bp[((dy * 5 + p) * NCOG + cg) * 64];
          #pragma unroll
          for (int p = 0; p < 5; ++p)
            #pragma unroll
            for (int cg = 0; cg < NCOG; ++cg)
              #pragma unroll
              for (int m = 0; m < 3; ++m)
                acc[m][cg] = __builtin_amdgcn_mfma_f32_16x16x32_bf16(
                    A[m][p], Bf[p][cg], acc[m][cg], 0, 0, 0);
        }
      }
    }
  }

  // epilogue: bias, bf16 store (valid rows pz 2..13), fused BN partial sums
  float s1[NCOG], s2[NCOG];
  #pragma unroll
  for (int cg = 0; cg < NCOG; ++cg) { s1[cg] = 0.f; s2[cg] = 0.f; }
  #pragma unroll
  for (int m = 0; m < 3; ++m) {
    const int vbase = ((t * 24 + x) * 24 + (y0 + m)) * 12;
    #pragma unroll
    for (int cg = 0; cg < NCOG; ++cg) {
      const float bv = bias[cg * 16 + col];
      #pragma unroll
      for (int i = 0; i < 4; ++i) {
        const int row = g * 4 + i;
        float val = acc[m][cg][i] + bv;
        if ((unsigned)(row - 2) < 12u) {
          convout[(size_t)(vbase + row - 2) * COUT + cg * 16 + col] = f2bf(val);
          s1[cg] += val;
          s2[cg] = fmaf(val, val, s2[cg]);
        }
      }
    }
  }
  #pragma unroll
  for (int cg = 0; cg < NCOG; ++cg) {
    s1[cg] += __shfl_xor(s1[cg], 16);
    s1[cg] += __shfl_xor(s1[cg], 32);
    s2[cg] += __shfl_xor(s2[cg], 16);
    s2[cg] += __shfl_xor(s2[cg], 32);
  }
  __shared__ float red[2][NCOG][16][2];
  if (l < 16)
    #pragma unroll
    for (int cg = 0; cg < NCOG; ++cg) {
      red[w][cg][l][0] = s1[cg];
      red[w][cg][l][1] = s2[cg];
    }
  __syncthreads();
  if (tid < COUT) {
    int cg = tid >> 4, cc = tid & 15;
    part[((size_t)bid * COUT + tid) * 2]     = red[0][cg][cc][0] + red[1][cg][cc][0];
    part[((size_t)bid * COUT + tid) * 2 + 1] = red[0][cg][cc][1] + red[1][cg][cc][1];
  }
}

// ---------------- BN stats: reduce 576 block-partials, fold gamma/beta ----
template<int C>
__global__ __launch_bounds__(256) void bn_stats2(
    const float* __restrict__ part, const float* __restrict__ gam,
    const float* __restrict__ bet, float* __restrict__ stats) {
  constexpr int NS = 256 / C;
  int tid = threadIdx.x;
  int c = tid & (C - 1);
  int sl = tid / C;
  float S = 0.f, S2 = 0.f;
  for (int b = sl; b < 576; b += NS) {
    S  += part[((size_t)b * C + c) * 2];
    S2 += part[((size_t)b * C + c) * 2 + 1];
  }
  __shared__ float sh[256][2];
  sh[tid][0] = S; sh[tid][1] = S2;
  __syncthreads();
  if (tid < C) {
    float s = 0.f, s2 = 0.f;
    #pragma unroll
    for (int k = 0; k < NS; ++k) { s += sh[k * C + tid][0]; s2 += sh[k * C + tid][1]; }
    float mean = s * (1.f / VOL);
    float var = s2 * (1.f / VOL) - mean * mean;
    float sc = gam[tid] * rsqrtf(var + EPSV);
    stats[2 * tid] = sc;
    stats[2 * tid + 1] = fmaf(-mean, sc, bet[tid]);
  }
}

// ---------------- BN apply + LeakyReLU: bf16 conv -> padded bf16 act ------
template<int C>
__global__ __launch_bounds__(256) void bn_apply(
    const unsigned short* __restrict__ convb, const float* __restrict__ stats,
    unsigned short* __restrict__ act) {
  int i = blockIdx.x * 256 + threadIdx.x;     // covers VOL*C/8
  size_t e = (size_t)i * 8;
  int v = (int)(e / C);
  int cb = (int)(e & (C - 1));
  int z = v % 12, y = (v / 12) % 24, xx = (v / 288) % 24, t = v / 6912;
  size_t pa = ((size_t)((t * 24 + xx) * 28 + y + 2) * 16 + z + 2) * C + cb;
  short8 in = *reinterpret_cast<const short8*>(convb + e);
  short8 o;
  #pragma unroll
  for (int k = 0; k < 8; ++k) {
    float sc = stats[2 * (cb + k)], sh = stats[2 * (cb + k) + 1];
    float xv = fmaf(bf2f((unsigned short)in[k]), sc, sh);
    xv = fmaxf(xv, SLOPE * xv);
    o[k] = (short)f2bf(xv);
  }
  *reinterpret_cast<short8*>(act + pa) = o;
}

// ---------------- projection (reads ACT16) --------------------------------
__global__ __launch_bounds__(256) void proj_kernel(
    const unsigned short* __restrict__ act, const float* __restrict__ w,
    const float* __restrict__ b, float* __restrict__ out) {
  int v = blockIdx.x * 256 + threadIdx.x;
  int z = v % 12, y = (v / 12) % 24, xx = (v / 288) % 24, t = v / 6912;
  size_t pa = ((size_t)((t * 24 + xx) * 28 + y + 2) * 16 + z + 2) * 16;
  const short8* p = reinterpret_cast<const short8*>(act + pa);
  short8 a0 = p[0], a1 = p[1];
  float s = b[0];
  #pragma unroll
  for (int k = 0; k < 8; ++k) s = fmaf(bf2f((unsigned short)a0[k]), w[k], s);
  #pragma unroll
  for (int k = 0; k < 8; ++k) s = fmaf(bf2f((unsigned short)a1[k]), w[8 + k], s);
  out[v] = s;
}

extern "C" void kernel_launch(void* const* d_in, const int* in_sizes, int n_in,
                              void* d_out, int out_size, void* d_ws, size_t ws_size,
                              hipStream_t stream) {
  const float* x      = (const float*)d_in[0];
  const float* w_emb  = (const float*)d_in[1];
  const float* b_emb  = (const float*)d_in[2];
  const float* w1     = (const float*)d_in[3];
  const float* b1     = (const float*)d_in[4];
  const float* g1     = (const float*)d_in[5];
  const float* be1    = (const float*)d_in[6];
  const float* w2     = (const float*)d_in[7];
  const float* b2     = (const float*)d_in[8];
  const float* g2     = (const float*)d_in[9];
  const float* be2    = (const float*)d_in[10];
  const float* w3     = (const float*)d_in[11];
  const float* b3     = (const float*)d_in[12];
  const float* g3     = (const float*)d_in[13];
  const float* be3    = (const float*)d_in[14];
  const float* w_proj = (const float*)d_in[15];
  const float* b_proj = (const float*)d_in[16];

  char* ws = (char*)d_ws;
  unsigned short* ACT16 = (unsigned short*)(ws + ACT16_B);
  unsigned short* ACT32 = (unsigned short*)(ws + ACT32_B);
  unsigned short* CONVB = (unsigned short*)(ws + CONVB_B);
  short8* WB = (short8*)(ws + WB_B);
  float* PART = (float*)(ws + PART_B);
  float* STATS = (float*)(ws + STATS_B);
  float* out = (float*)d_out;

  zero_act<<<ZERO_BLKS, 256, 0, stream>>>((float4*)ws);
  embed_kernel<<<VOL / 256, 256, 0, stream>>>(x, w_emb, b_emb, ACT16);

  // layer 1: 16 -> 16
  wtrans_mfma<16, 16><<<(125 * 3 * 1 * 64 + 255) / 256, 256, 0, stream>>>(w1, WB);
  conv4d_v4<16, 16><<<576, 128, 0, stream>>>(ACT16, WB, b1, CONVB, PART);
  bn_stats2<16><<<1, 256, 0, stream>>>(PART, g1, be1, STATS);
  bn_apply<16><<<VOL * 16 / 2048, 256, 0, stream>>>(CONVB, STATS, ACT16);

  // layer 2: 16 -> 32
  wtrans_mfma<16, 32><<<(125 * 3 * 2 * 64 + 255) / 256, 256, 0, stream>>>(w2, WB);
  conv4d_v4<16, 32><<<576, 128, 0, stream>>>(ACT16, WB, b2, CONVB, PART);
  bn_stats2<32><<<1, 256, 0, stream>>>(PART, g2, be2, STATS);
  bn_apply<32><<<VOL * 32 / 2048, 256, 0, stream>>>(CONVB, STATS, ACT32);

  // layer 3: 32 -> 16
  wtrans_mfma<32, 16><<<(125 * 5 * 1 * 64 + 255) / 256, 256, 0, stream>>>(w3, WB);
  conv4d_v4<32, 16><<<576, 128, 0, stream>>>(ACT32, WB, b3, CONVB, PART);
  bn_stats2<16><<<1, 256, 0, stream>>>(PART, g3, be3, STATS);
  bn_apply<16><<<VOL * 16 / 2048, 256, 0, stream>>>(CONVB, STATS, ACT16);

  proj_kernel<<<VOL / 256, 256, 0, stream>>>(ACT16, w_proj, b_proj, out);
}

// Round 5
// 223.960 us; speedup vs baseline: 1.4726x; 1.4726x over previous
//
#include <hip/hip_runtime.h>

typedef short short8 __attribute__((ext_vector_type(8)));
typedef float floatx4 __attribute__((ext_vector_type(4)));

#define TDIM 6
#define XDIM 24
#define YDIM 24
#define ZDIM 12
#define VOL 41472   // 6*24*24*12
#define EPSV 1e-5f
#define SLOPE 0.1f
#define NBLK 288    // conv blocks: 6t * 24x * 2yhalf

// Padded act layout (stride = CIN): pv(t,x,y,z) = ((t*24+x)*28 + y+2)*16 + z+2
// elem = pv*CIN + c.  Halo (py 0,1,26,27 / pz 0,1,14,15) stays zero.
// workspace byte offsets
#define ACT16_B   256u        // guard 256B before; data 64512*16*2 = 2,064,384
#define ACT32_B   2064896u    // data 64512*32*2 = 4,128,768
#define CONVB_B   6193664u    // bf16 conv out: VOL*32*2 = 2,654,208
#define WB_B      8847872u    // B-frags: up to 768,000
#define PART_B    9615872u    // 288*32*2*4 = 73,728
#define STATS_B   9691136u    // 512
#define ZERO_BLKS 1513        // zero [0, ~6.19MB) in 4KB blocks

__device__ inline unsigned short f2bf(float f) {
  unsigned u = __builtin_bit_cast(unsigned, f);
  unsigned r = u + 0x7fffu + ((u >> 16) & 1u);
  return (unsigned short)(r >> 16);
}
__device__ inline float bf2f(unsigned short h) {
  unsigned u = ((unsigned)h) << 16;
  return __builtin_bit_cast(float, u);
}

__global__ __launch_bounds__(256) void zero_act(float4* __restrict__ p) {
  p[blockIdx.x * 256 + threadIdx.x] = make_float4(0.f, 0.f, 0.f, 0.f);
}

// ---------------- embed -> ACT16 (stride 16) ------------------------------
__global__ __launch_bounds__(256) void embed_kernel(
    const float* __restrict__ x, const float* __restrict__ w,
    const float* __restrict__ b, unsigned short* __restrict__ act) {
  int v = blockIdx.x * 256 + threadIdx.x;
  const float4* xp = reinterpret_cast<const float4*>(x + (size_t)v * 8);
  float4 x0 = xp[0], x1 = xp[1];
  float xv[8] = {x0.x, x0.y, x0.z, x0.w, x1.x, x1.y, x1.z, x1.w};
  float acc[16];
  #pragma unroll
  for (int h = 0; h < 16; ++h) acc[h] = b[h];
  #pragma unroll
  for (int f = 0; f < 8; ++f)
    #pragma unroll
    for (int h = 0; h < 16; ++h)
      acc[h] = fmaf(xv[f], w[f * 16 + h], acc[h]);
  int z = v % 12, y = (v / 12) % 24, xx = (v / 288) % 24, t = v / 6912;
  size_t pa = ((size_t)((t * 24 + xx) * 28 + y + 2) * 16 + z + 2) * 16;
  short8 o0, o1;
  #pragma unroll
  for (int h = 0; h < 8; ++h) { o0[h] = (short)f2bf(acc[h]); o1[h] = (short)f2bf(acc[8 + h]); }
  short8* op = reinterpret_cast<short8*>(act + pa);
  op[0] = o0; op[1] = o1;
}

// ---------------- weight -> B-fragment-ordered bf16 -----------------------
// wb[((q*NP + p)*NCOG + cog)*64 + lane], q=(dt*5+dx)*5+dy
// CIN16: k=g*8+j -> dz=2p+(g>>1), ci=(g&1)*8+j ; CIN32: ci=g*8+j, dz=p
template<int CIN, int COUT>
__global__ __launch_bounds__(256) void wtrans_mfma(
    const float* __restrict__ w, short8* __restrict__ wb) {
  constexpr int NP = (CIN == 16) ? 3 : 5;
  constexpr int NCOG = COUT / 16;
  int id = blockIdx.x * 256 + threadIdx.x;
  if (id >= 125 * NP * NCOG * 64) return;
  int lane = id & 63;
  int q = id >> 6;
  int cog = q % NCOG; q /= NCOG;
  int p = q % NP; q /= NP;            // q = (dt*5+dx)*5+dy
  int g = lane >> 4, n = lane & 15;
  int co = cog * 16 + n;
  short8 out;
  #pragma unroll
  for (int j = 0; j < 8; ++j) {
    int ci = (CIN == 16) ? ((g & 1) * 8 + j) : (g * 8 + j);
    int dz = (CIN == 16) ? (2 * p + (g >> 1)) : p;
    float val = 0.f;
    if (dz < 5) val = w[((size_t)co * CIN + ci) * 625 + q * 5 + dz];
    out[j] = (short)f2bf(val);
  }
  wb[id] = out;
}

// ---------------- conv4d v5: LDS-staged slabs, dbuf, in-register acc ------
// Block = (t, x, yhalf): 288 blocks, 256 thr = 4 waves; wave owns 3 y-rows.
// Per valid (dt,dx): stage 16py*16pz*CIN slab into LDS (coalesced, dbuf),
// A-frags via ds_read_b128 (one base + imm offsets), MFMA accumulate.
template<int CIN, int COUT>
__global__ __launch_bounds__(256, 2) void conv4d_v5(
    const unsigned short* __restrict__ act, const short8* __restrict__ wb,
    const float* __restrict__ bias, unsigned short* __restrict__ convout,
    float* __restrict__ part) {
  constexpr int NP = (CIN == 16) ? 3 : 5;
  constexpr int NCOG = COUT / 16;
  constexpr int ROWS = 275;               // 2 front pad + 256 data + 17 back pad
  constexpr int CB = CIN * 2;             // bytes per pz-row
  constexpr int CHUNK = (256 * CB) / 256; // stage bytes per thread (32 / 64)
  constexpr int NR = CHUNK / 16;          // short8 regs per thread (2 / 4)

  __shared__ __align__(16) short lbuf[2][ROWS * CIN];
  __shared__ int vlist[26];
  __shared__ float red[4][NCOG][16][2];

  const int tid = threadIdx.x;
  const int l = tid & 63;
  const int w = tid >> 6;
  const int col = l & 15, g = l >> 4;
  const int bid = blockIdx.x;
  const int yhalf = bid & 1;
  const int x = (bid >> 1) % 24;
  const int t = bid / 48;

  // zero pad rows (front 2 rows, back 17 rows) of both buffers
  {
    int* b0 = (int*)lbuf[0]; int* b1 = (int*)lbuf[1];
    for (int i = tid; i < CIN; i += 256) { b0[i] = 0; b1[i] = 0; }
    for (int i = 258 * CIN / 2 + tid; i < 275 * CIN / 2; i += 256) { b0[i] = 0; b1[i] = 0; }
  }
  if (tid == 0) {
    int n = 0;
    for (int dt = 0; dt < 5; ++dt) {
      int ti = t + dt - 2;
      if ((unsigned)ti >= (unsigned)TDIM) continue;
      for (int dx = 0; dx < 5; ++dx) {
        int xi = x + dx - 2;
        if ((unsigned)xi >= (unsigned)XDIM) continue;
        vlist[n++] = ((ti * 24 + xi) << 5) | (dt * 5 + dx);
      }
    }
    vlist[25] = n;
  }
  __syncthreads();
  const int nv = vlist[25];

  // per-thread stage addressing
  const int stgoff = tid * CHUNK;                       // byte offset in slab
  char* const ldst0 = (char*)lbuf[0] + 2 * CB + stgoff; // +2 pad rows
  char* const ldst1 = (char*)lbuf[1] + 2 * CB + stgoff;

  // A-frag ds_read base (byte): one VGPR base + compile-time immediates
  const int tsub = (CIN == 16) ? (g >> 1) : 0;
  const int abase = (CIN == 16)
      ? ((w * 48 + col + tsub) * 32 + (g & 1) * 16)
      : ((w * 48 + col) * 64 + g * 16);

  floatx4 acc[3][NCOG];
  #pragma unroll
  for (int m = 0; m < 3; ++m)
    #pragma unroll
    for (int cg = 0; cg < NCOG; ++cg) acc[m][cg] = (floatx4){0.f, 0.f, 0.f, 0.f};

  // prologue: stage slab 0, start loads for slab 1
  short8 R[NR];
  {
    int pi = vlist[0] >> 5;
    const char* src = (const char*)act + ((size_t)(pi * 28 + yhalf * 12) * 16) * CB + stgoff;
    #pragma unroll
    for (int c = 0; c < NR; ++c) R[c] = *(const short8*)(src + c * 16);
    #pragma unroll
    for (int c = 0; c < NR; ++c) *(short8*)(ldst0 + c * 16) = R[c];
    if (nv > 1) {
      int pi1 = vlist[1] >> 5;
      const char* s1 = (const char*)act + ((size_t)(pi1 * 28 + yhalf * 12) * 16) * CB + stgoff;
      #pragma unroll
      for (int c = 0; c < NR; ++c) R[c] = *(const short8*)(s1 + c * 16);
    }
  }

  for (int k = 0; k < nv; ++k) {
    __syncthreads();                       // slab k staged & visible
    const int q = vlist[k] & 31;
    const char* lb = (const char*)lbuf[k & 1];

    short8 A[7][NP];
    #pragma unroll
    for (int r = 0; r < 7; ++r)
      #pragma unroll
      for (int p = 0; p < NP; ++p) {
        const int off = (CIN == 16) ? (r * 512 + p * 64) : (r * 1024 + p * 64);
        A[r][p] = *(const short8*)(lb + abase + off);
      }
    const short8* bp = wb + (size_t)q * (5 * NP * NCOG) * 64 + l;
    #pragma unroll
    for (int dy = 0; dy < 5; ++dy) {
      short8 Bf[NP][NCOG];
      #pragma unroll
      for (int p = 0; p < NP; ++p)
        #pragma unroll
        for (int cg = 0; cg < NCOG; ++cg)
          Bf[p][cg] = bp[((dy * NP + p) * NCOG + cg) * 64];
      #pragma unroll
      for (int p = 0; p < NP; ++p)
        #pragma unroll
        for (int cg = 0; cg < NCOG; ++cg)
          #pragma unroll
          for (int m = 0; m < 3; ++m)
            acc[m][cg] = __builtin_amdgcn_mfma_f32_16x16x32_bf16(
                A[m + dy][p], Bf[p][cg], acc[m][cg], 0, 0, 0);
    }
    // stage slab k+1 into other buffer; start loads for slab k+2
    if (k + 1 < nv) {
      char* dst = ((k + 1) & 1) ? ldst1 : ldst0;
      #pragma unroll
      for (int c = 0; c < NR; ++c) *(short8*)(dst + c * 16) = R[c];
      if (k + 2 < nv) {
        int pi2 = vlist[k + 2] >> 5;
        const char* s2 = (const char*)act + ((size_t)(pi2 * 28 + yhalf * 12) * 16) * CB + stgoff;
        #pragma unroll
        for (int c = 0; c < NR; ++c) R[c] = *(const short8*)(s2 + c * 16);
      }
    }
  }

  // epilogue: bias, bf16 store (valid pz rows 2..13), fused BN partial sums
  float s1[NCOG], s2[NCOG];
  #pragma unroll
  for (int cg = 0; cg < NCOG; ++cg) { s1[cg] = 0.f; s2[cg] = 0.f; }
  const int y0 = yhalf * 12 + w * 3;
  #pragma unroll
  for (int m = 0; m < 3; ++m) {
    const int vbase = ((t * 24 + x) * 24 + (y0 + m)) * 12;
    #pragma unroll
    for (int cg = 0; cg < NCOG; ++cg) {
      const float bv = bias[cg * 16 + col];
      #pragma unroll
      for (int i = 0; i < 4; ++i) {
        const int row = g * 4 + i;
        float val = acc[m][cg][i] + bv;
        if ((unsigned)(row - 2) < 12u) {
          convout[(size_t)(vbase + row - 2) * COUT + cg * 16 + col] = f2bf(val);
          s1[cg] += val;
          s2[cg] = fmaf(val, val, s2[cg]);
        }
      }
    }
  }
  #pragma unroll
  for (int cg = 0; cg < NCOG; ++cg) {
    s1[cg] += __shfl_xor(s1[cg], 16);
    s1[cg] += __shfl_xor(s1[cg], 32);
    s2[cg] += __shfl_xor(s2[cg], 16);
    s2[cg] += __shfl_xor(s2[cg], 32);
  }
  if (l < 16)
    #pragma unroll
    for (int cg = 0; cg < NCOG; ++cg) {
      red[w][cg][l][0] = s1[cg];
      red[w][cg][l][1] = s2[cg];
    }
  __syncthreads();
  if (tid < COUT) {
    int cg = tid >> 4, cc = tid & 15;
    float p1 = 0.f, p2 = 0.f;
    #pragma unroll
    for (int ww = 0; ww < 4; ++ww) { p1 += red[ww][cg][cc][0]; p2 += red[ww][cg][cc][1]; }
    part[((size_t)bid * COUT + tid) * 2]     = p1;
    part[((size_t)bid * COUT + tid) * 2 + 1] = p2;
  }
}

// ---------------- BN stats: reduce block-partials, fold gamma/beta --------
template<int C>
__global__ __launch_bounds__(256) void bn_stats2(
    const float* __restrict__ part, const float* __restrict__ gam,
    const float* __restrict__ bet, float* __restrict__ stats) {
  constexpr int NS = 256 / C;
  int tid = threadIdx.x;
  int c = tid & (C - 1);
  int sl = tid / C;
  float S = 0.f, S2 = 0.f;
  for (int b = sl; b < NBLK; b += NS) {
    S  += part[((size_t)b * C + c) * 2];
    S2 += part[((size_t)b * C + c) * 2 + 1];
  }
  __shared__ float sh[256][2];
  sh[tid][0] = S; sh[tid][1] = S2;
  __syncthreads();
  if (tid < C) {
    float s = 0.f, s2 = 0.f;
    #pragma unroll
    for (int k = 0; k < NS; ++k) { s += sh[k * C + tid][0]; s2 += sh[k * C + tid][1]; }
    float mean = s * (1.f / VOL);
    float var = s2 * (1.f / VOL) - mean * mean;
    float sc = gam[tid] * rsqrtf(var + EPSV);
    stats[2 * tid] = sc;
    stats[2 * tid + 1] = fmaf(-mean, sc, bet[tid]);
  }
}

// ---------------- BN apply + LeakyReLU: bf16 conv -> padded bf16 act ------
template<int C>
__global__ __launch_bounds__(256) void bn_apply(
    const unsigned short* __restrict__ convb, const float* __restrict__ stats,
    unsigned short* __restrict__ act) {
  int i = blockIdx.x * 256 + threadIdx.x;     // covers VOL*C/8
  size_t e = (size_t)i * 8;
  int v = (int)(e / C);
  int cb = (int)(e & (C - 1));
  int z = v % 12, y = (v / 12) % 24, xx = (v / 288) % 24, t = v / 6912;
  size_t pa = ((size_t)((t * 24 + xx) * 28 + y + 2) * 16 + z + 2) * C + cb;
  short8 in = *reinterpret_cast<const short8*>(convb + e);
  short8 o;
  #pragma unroll
  for (int k = 0; k < 8; ++k) {
    float sc = stats[2 * (cb + k)], sh = stats[2 * (cb + k) + 1];
    float xv = fmaf(bf2f((unsigned short)in[k]), sc, sh);
    xv = fmaxf(xv, SLOPE * xv);
    o[k] = (short)f2bf(xv);
  }
  *reinterpret_cast<short8*>(act + pa) = o;
}

// ---------------- projection (reads ACT16) --------------------------------
__global__ __launch_bounds__(256) void proj_kernel(
    const unsigned short* __restrict__ act, const float* __restrict__ w,
    const float* __restrict__ b, float* __restrict__ out) {
  int v = blockIdx.x * 256 + threadIdx.x;
  int z = v % 12, y = (v / 12) % 24, xx = (v / 288) % 24, t = v / 6912;
  size_t pa = ((size_t)((t * 24 + xx) * 28 + y + 2) * 16 + z + 2) * 16;
  const short8* p = reinterpret_cast<const short8*>(act + pa);
  short8 a0 = p[0], a1 = p[1];
  float s = b[0];
  #pragma unroll
  for (int k = 0; k < 8; ++k) s = fmaf(bf2f((unsigned short)a0[k]), w[k], s);
  #pragma unroll
  for (int k = 0; k < 8; ++k) s = fmaf(bf2f((unsigned short)a1[k]), w[8 + k], s);
  out[v] = s;
}

extern "C" void kernel_launch(void* const* d_in, const int* in_sizes, int n_in,
                              void* d_out, int out_size, void* d_ws, size_t ws_size,
                              hipStream_t stream) {
  const float* x      = (const float*)d_in[0];
  const float* w_emb  = (const float*)d_in[1];
  const float* b_emb  = (const float*)d_in[2];
  const float* w1     = (const float*)d_in[3];
  const float* b1     = (const float*)d_in[4];
  const float* g1     = (const float*)d_in[5];
  const float* be1    = (const float*)d_in[6];
  const float* w2     = (const float*)d_in[7];
  const float* b2     = (const float*)d_in[8];
  const float* g2     = (const float*)d_in[9];
  const float* be2    = (const float*)d_in[10];
  const float* w3     = (const float*)d_in[11];
  const float* b3     = (const float*)d_in[12];
  const float* g3     = (const float*)d_in[13];
  const float* be3    = (const float*)d_in[14];
  const float* w_proj = (const float*)d_in[15];
  const float* b_proj = (const float*)d_in[16];

  char* ws = (char*)d_ws;
  unsigned short* ACT16 = (unsigned short*)(ws + ACT16_B);
  unsigned short* ACT32 = (unsigned short*)(ws + ACT32_B);
  unsigned short* CONVB = (unsigned short*)(ws + CONVB_B);
  short8* WB = (short8*)(ws + WB_B);
  float* PART = (float*)(ws + PART_B);
  float* STATS = (float*)(ws + STATS_B);
  float* out = (float*)d_out;

  zero_act<<<ZERO_BLKS, 256, 0, stream>>>((float4*)ws);
  embed_kernel<<<VOL / 256, 256, 0, stream>>>(x, w_emb, b_emb, ACT16);

  // layer 1: 16 -> 16
  wtrans_mfma<16, 16><<<(125 * 3 * 1 * 64 + 255) / 256, 256, 0, stream>>>(w1, WB);
  conv4d_v5<16, 16><<<NBLK, 256, 0, stream>>>(ACT16, WB, b1, CONVB, PART);
  bn_stats2<16><<<1, 256, 0, stream>>>(PART, g1, be1, STATS);
  bn_apply<16><<<VOL * 16 / 2048, 256, 0, stream>>>(CONVB, STATS, ACT16);

  // layer 2: 16 -> 32
  wtrans_mfma<16, 32><<<(125 * 3 * 2 * 64 + 255) / 256, 256, 0, stream>>>(w2, WB);
  conv4d_v5<16, 32><<<NBLK, 256, 0, stream>>>(ACT16, WB, b2, CONVB, PART);
  bn_stats2<32><<<1, 256, 0, stream>>>(PART, g2, be2, STATS);
  bn_apply<32><<<VOL * 32 / 2048, 256, 0, stream>>>(CONVB, STATS, ACT32);

  // layer 3: 32 -> 16
  wtrans_mfma<32, 16><<<(125 * 5 * 1 * 64 + 255) / 256, 256, 0, stream>>>(w3, WB);
  conv4d_v5<32, 16><<<NBLK, 256, 0, stream>>>(ACT32, WB, b3, CONVB, PART);
  bn_stats2<16><<<1, 256, 0, stream>>>(PART, g3, be3, STATS);
  bn_apply<16><<<VOL * 16 / 2048, 256, 0, stream>>>(CONVB, STATS, ACT16);

  proj_kernel<<<VOL / 256, 256, 0, stream>>>(ACT16, w_proj, b_proj, out);
}

// Round 7
// 208.959 us; speedup vs baseline: 1.5783x; 1.0718x over previous
//
#include <hip/hip_runtime.h>

typedef short short8 __attribute__((ext_vector_type(8)));
typedef float floatx4 __attribute__((ext_vector_type(4)));

#define TDIM 6
#define XDIM 24
#define YDIM 24
#define ZDIM 12
#define VOL 41472   // 6*24*24*12
#define EPSV 1e-5f
#define SLOPE 0.1f

// Padded act layout (stride = CIN): pv(t,x,y,z) = ((t*24+x)*28 + y+2)*16 + z+2
// Halo (py 0,1,26,27 / pz 0,1,14,15) stays zero.
// workspace byte offsets
#define ACT16_B   256u        // 64512*16*2 = 2,064,384
#define ACT32_B   2064896u    // 64512*32*2 = 4,128,768
#define CONVB_B   6193664u    // bf16 conv out: VOL*32*2 = 2,654,208
#define WB_B      8847872u    // B-frags: up to 768,000
#define PART_B    9615872u    // 1152*32*2*4 = 294,912
#define STATS_B   9910784u    // 512
#define ZERO_BLKS 1513        // zero [0, ~6.19MB): ACT16+ACT32 halos

__device__ inline unsigned short f2bf(float f) {
  unsigned u = __builtin_bit_cast(unsigned, f);
  unsigned r = u + 0x7fffu + ((u >> 16) & 1u);
  return (unsigned short)(r >> 16);
}
__device__ inline float bf2f(unsigned short h) {
  unsigned u = ((unsigned)h) << 16;
  return __builtin_bit_cast(float, u);
}

__global__ __launch_bounds__(256) void zero_act(float4* __restrict__ p) {
  p[blockIdx.x * 256 + threadIdx.x] = make_float4(0.f, 0.f, 0.f, 0.f);
}

// ---------------- embed -> ACT16 (stride 16) ------------------------------
__global__ __launch_bounds__(256) void embed_kernel(
    const float* __restrict__ x, const float* __restrict__ w,
    const float* __restrict__ b, unsigned short* __restrict__ act) {
  int v = blockIdx.x * 256 + threadIdx.x;
  const float4* xp = reinterpret_cast<const float4*>(x + (size_t)v * 8);
  float4 x0 = xp[0], x1 = xp[1];
  float xv[8] = {x0.x, x0.y, x0.z, x0.w, x1.x, x1.y, x1.z, x1.w};
  float acc[16];
  #pragma unroll
  for (int h = 0; h < 16; ++h) acc[h] = b[h];
  #pragma unroll
  for (int f = 0; f < 8; ++f)
    #pragma unroll
    for (int h = 0; h < 16; ++h)
      acc[h] = fmaf(xv[f], w[f * 16 + h], acc[h]);
  int z = v % 12, y = (v / 12) % 24, xx = (v / 288) % 24, t = v / 6912;
  size_t pa = ((size_t)((t * 24 + xx) * 28 + y + 2) * 16 + z + 2) * 16;
  short8 o0, o1;
  #pragma unroll
  for (int h = 0; h < 8; ++h) { o0[h] = (short)f2bf(acc[h]); o1[h] = (short)f2bf(acc[8 + h]); }
  short8* op = reinterpret_cast<short8*>(act + pa);
  op[0] = o0; op[1] = o1;
}

// ---------------- weight -> B-fragment-ordered bf16 -----------------------
// wb[((q*NP + p)*NCOG + cog)*64 + lane], q=(dt*5+dx)*5+dy
// CIN16: k=g*8+j -> dz=2p+(g>>1), ci=(g&1)*8+j ; CIN32: ci=g*8+j, dz=p
template<int CIN, int COUT>
__global__ __launch_bounds__(256) void wtrans_mfma(
    const float* __restrict__ w, short8* __restrict__ wb) {
  constexpr int NP = (CIN == 16) ? 3 : 5;
  constexpr int NCOG = COUT / 16;
  int id = blockIdx.x * 256 + threadIdx.x;
  if (id >= 125 * NP * NCOG * 64) return;
  int lane = id & 63;
  int q = id >> 6;
  int cog = q % NCOG; q /= NCOG;
  int p = q % NP; q /= NP;            // q = (dt*5+dx)*5+dy
  int g = lane >> 4, n = lane & 15;
  int co = cog * 16 + n;
  short8 out;
  #pragma unroll
  for (int j = 0; j < 8; ++j) {
    int ci = (CIN == 16) ? ((g & 1) * 8 + j) : (g * 8 + j);
    int dz = (CIN == 16) ? (2 * p + (g >> 1)) : p;
    float val = 0.f;
    if (dz < 5) val = w[((size_t)co * CIN + ci) * 625 + q * 5 + dz];
    out[j] = (short)f2bf(val);
  }
  wb[id] = out;
}

// ---------------- conv4d v7: intra-block K-split, LDS slabs ---------------
// 576 blocks (t,x,yq) x 8 waves (2 y-triples x 4 tap-slices), 512 thr.
// Per tap (dt,dx): slice's 2 waves stage a 10py x 16pz slab (padded rows,
// single buffer, issue-early/write-late); A via ds_read_b128 imm offsets,
// rolling 3-row window; epilogue: LDS reduce over the 4 slices + bias +
// bf16 store + fused BN partial sums. NO cross-block K split (R6 lesson).
template<int CIN, int COUT>
__global__ __launch_bounds__(512, 4) void conv4d_v7(
    const unsigned short* __restrict__ act, const short8* __restrict__ wb,
    const float* __restrict__ bias, unsigned short* __restrict__ convout,
    float* __restrict__ part) {
  constexpr int NP   = (CIN == 16) ? 3 : 5;
  constexpr int NCOG = COUT / 16;
  constexpr int KSB  = 4;                     // tap-slices per block
  constexpr int NT   = 512;
  constexpr int CB   = CIN * 2;               // bytes per pz-row (global)
  constexpr int RSP  = (CIN == 16) ? 48 : 80; // padded LDS row stride
  constexpr int PST  = (CIN == 16) ? 96 : 80; // dz-step bytes
  constexpr int SLABSZ = 160 * RSP;           // 10 py * 16 pz rows
  constexpr int NCHUNK = 160 * CB / 16;       // 320 / 640
  constexpr int CPT  = (NCHUNK + 127) / 128;  // 3 / 5
  constexpr int FRONT = 2 * RSP;
  constexpr int LDSZ = FRONT + KSB * SLABSZ + 5 * RSP;

  __shared__ __align__(16) char lds[LDSZ];
  __shared__ int vlist[26];

  const int tid = threadIdx.x;
  const int l = tid & 63;
  const int w = tid >> 6;                // wave id = yt*KSB + ks
  const int ks = w & (KSB - 1);
  const int yt = w / KSB;
  const int col = l & 15, g = l >> 4;
  const int bid = blockIdx.x;
  const int yq = bid & 3;
  const int x = (bid >> 2) % 24;
  const int t = bid / 96;
  const int y0q = yq * 6;                // py base of staged window

  // zero guard rows (front 2, tail 5) once
  for (int i = tid; i * 4 < FRONT; i += NT) ((int*)lds)[i] = 0;
  for (int i = tid; i * 4 < 5 * RSP; i += NT)
    ((int*)(lds + FRONT + KSB * SLABSZ))[i] = 0;
  if (tid == 0) {
    int n = 0;
    for (int dt = 0; dt < 5; ++dt) {
      int ti = t + dt - 2;
      if ((unsigned)ti >= (unsigned)TDIM) continue;
      for (int dx = 0; dx < 5; ++dx) {
        int xi = x + dx - 2;
        if ((unsigned)xi >= (unsigned)XDIM) continue;
        vlist[n++] = ((ti * 24 + xi) << 5) | (dt * 5 + dx);
      }
    }
    vlist[25] = n;
  }
  __syncthreads();
  const int nv = vlist[25];
  const int lo = (nv * ks) >> 2;
  const int hi = (nv * (ks + 1)) >> 2;
  const int nsteps = (nv + 3) >> 2;

  char* const slab = lds + FRONT + ks * SLABSZ;
  const int sid = yt * 64 + l;           // staging id within slice group

  // A-frag ds_read base (may point into guards; garbage only feeds
  // discarded output rows or dz=5 zero-weight taps)
  const char* arp = (CIN == 16)
      ? slab + (yt * 48 + col + (g >> 1) - 2) * 48 + (g & 1) * 16
      : slab + (yt * 48 + col - 2) * 80 + g * 16;

  floatx4 acc[3][NCOG];
  #pragma unroll
  for (int m = 0; m < 3; ++m)
    #pragma unroll
    for (int cg = 0; cg < NCOG; ++cg) acc[m][cg] = (floatx4){0.f, 0.f, 0.f, 0.f};

  short8 R[CPT];
  // prologue: issue loads for first tap of this slice
  if (lo < hi) {
    int pi = vlist[lo] >> 5;
    const char* src = (const char*)act + (size_t)(pi * 28 + y0q) * 16 * CB + sid * 16;
    #pragma unroll
    for (int c = 0; c < CPT; ++c)
      if (sid + c * 128 < NCHUNK) R[c] = *(const short8*)(src + c * 2048);
  }

  for (int s = 0; s < nsteps; ++s) {
    const bool active = (lo + s) < hi;
    __syncthreads();                     // all reads of previous slab done
    if (active) {
      #pragma unroll
      for (int c = 0; c < CPT; ++c) {
        int ch = sid + c * 128;
        if (ch < NCHUNK) {
          char* dst = (CIN == 16)
              ? slab + (ch >> 1) * 48 + (ch & 1) * 16
              : slab + (ch >> 2) * 80 + (ch & 3) * 16;
          *(short8*)dst = R[c];
        }
      }
    }
    __syncthreads();                     // slab visible
    if (active && (lo + s + 1) < hi) {   // issue next tap's loads early
      int pi = vlist[lo + s + 1] >> 5;
      const char* src = (const char*)act + (size_t)(pi * 28 + y0q) * 16 * CB + sid * 16;
      #pragma unroll
      for (int c = 0; c < CPT; ++c)
        if (sid + c * 128 < NCHUNK) R[c] = *(const short8*)(src + c * 2048);
    }
    if (active) {
      const int q = vlist[lo + s] & 31;
      const short8* bp = wb + (size_t)q * (5 * NP * NCOG) * 64 + l;
      short8 W[3][NP];
      #pragma unroll
      for (int r = 0; r < 3; ++r)
        #pragma unroll
        for (int p = 0; p < NP; ++p)
          W[r][p] = *(const short8*)(arp + r * (16 * RSP) + p * PST);
      #pragma unroll
      for (int dy = 0; dy < 5; ++dy) {
        short8 Bf[NP][NCOG];
        #pragma unroll
        for (int p = 0; p < NP; ++p)
          #pragma unroll
          for (int cg = 0; cg < NCOG; ++cg)
            Bf[p][cg] = bp[((dy * NP + p) * NCOG + cg) * 64];
        #pragma unroll
        for (int p = 0; p < NP; ++p)
          #pragma unroll
          for (int cg = 0; cg < NCOG; ++cg)
            #pragma unroll
            for (int m = 0; m < 3; ++m)
              acc[m][cg] = __builtin_amdgcn_mfma_f32_16x16x32_bf16(
                  W[(dy + m) % 3][p], Bf[p][cg], acc[m][cg], 0, 0, 0);
        if (dy < 4) {
          #pragma unroll
          for (int p = 0; p < NP; ++p)
            W[dy % 3][p] = *(const short8*)(arp + (dy + 3) * (16 * RSP) + p * PST);
        }
      }
    }
  }

  // ---- epilogue: reduce slices (LDS overlay), bias, bf16 store, BN stats --
  float4* redf = (float4*)lds;
  const int nred = 2 * NCOG;
  const int ryt = (NCOG == 2) ? (w >> 1) : w;
  const int rcg = (NCOG == 2) ? (w & 1) : 0;
  const bool isred = w < nred;
  const float bvv = isred ? bias[rcg * 16 + col] : 0.f;
  float rs1 = 0.f, rs2 = 0.f;
  #pragma unroll
  for (int m = 0; m < 3; ++m) {
    __syncthreads();
    #pragma unroll
    for (int cg = 0; cg < NCOG; ++cg) {
      floatx4 a = acc[m][cg];
      redf[(w * NCOG + cg) * 64 + l] = make_float4(a[0], a[1], a[2], a[3]);
    }
    __syncthreads();
    if (isred) {
      float vs[4] = {0.f, 0.f, 0.f, 0.f};
      #pragma unroll
      for (int k = 0; k < KSB; ++k) {
        float4 vv = redf[((ryt * KSB + k) * NCOG + rcg) * 64 + l];
        vs[0] += vv.x; vs[1] += vv.y; vs[2] += vv.z; vs[3] += vv.w;
      }
      const int yy = y0q + ryt * 3 + m;
      const int vbase = ((t * 24 + x) * 24 + yy) * 12;
      #pragma unroll
      for (int i = 0; i < 4; ++i) {
        int pz = g * 4 + i;
        float val = vs[i] + bvv;
        if ((unsigned)(pz - 2) < 12u) {
          convout[(size_t)(vbase + pz - 2) * COUT + rcg * 16 + col] = f2bf(val);
          rs1 += val;
          rs2 = fmaf(val, val, rs2);
        }
      }
    }
  }
  if (isred) {
    rs1 += __shfl_xor(rs1, 16); rs1 += __shfl_xor(rs1, 32);
    rs2 += __shfl_xor(rs2, 16); rs2 += __shfl_xor(rs2, 32);
    if (l < 16) {
      size_t pb = ((size_t)(bid * 2 + ryt) * COUT + rcg * 16 + l) * 2;
      part[pb] = rs1; part[pb + 1] = rs2;
    }
  }
}

// ---------------- BN stats: reduce block-partials, fold gamma/beta --------
template<int C>
__global__ __launch_bounds__(256) void bn_stats2(
    const float* __restrict__ part, const float* __restrict__ gam,
    const float* __restrict__ bet, float* __restrict__ stats, int nblk) {
  constexpr int NS = 256 / C;
  int tid = threadIdx.x;
  int c = tid & (C - 1);
  int sl = tid / C;
  float S = 0.f, S2 = 0.f;
  for (int b = sl; b < nblk; b += NS) {
    S  += part[((size_t)b * C + c) * 2];
    S2 += part[((size_t)b * C + c) * 2 + 1];
  }
  __shared__ float sh[256][2];
  sh[tid][0] = S; sh[tid][1] = S2;
  __syncthreads();
  if (tid < C) {
    float s = 0.f, s2 = 0.f;
    #pragma unroll
    for (int k = 0; k < NS; ++k) { s += sh[k * C + tid][0]; s2 += sh[k * C + tid][1]; }
    float mean = s * (1.f / VOL);
    float var = s2 * (1.f / VOL) - mean * mean;
    float sc = gam[tid] * rsqrtf(var + EPSV);
    stats[2 * tid] = sc;
    stats[2 * tid + 1] = fmaf(-mean, sc, bet[tid]);
  }
}

// ---------------- BN apply + LeakyReLU: bf16 conv -> padded bf16 act ------
template<int C>
__global__ __launch_bounds__(256) void bn_apply(
    const unsigned short* __restrict__ convb, const float* __restrict__ stats,
    unsigned short* __restrict__ act) {
  int i = blockIdx.x * 256 + threadIdx.x;     // covers VOL*C/8
  size_t e = (size_t)i * 8;
  int v = (int)(e / C);
  int cb = (int)(e & (C - 1));
  int z = v % 12, y = (v / 12) % 24, xx = (v / 288) % 24, t = v / 6912;
  size_t pa = ((size_t)((t * 24 + xx) * 28 + y + 2) * 16 + z + 2) * C + cb;
  short8 in = *reinterpret_cast<const short8*>(convb + e);
  short8 o;
  #pragma unroll
  for (int k = 0; k < 8; ++k) {
    float sc = stats[2 * (cb + k)], sh = stats[2 * (cb + k) + 1];
    float xv = fmaf(bf2f((unsigned short)in[k]), sc, sh);
    xv = fmaxf(xv, SLOPE * xv);
    o[k] = (short)f2bf(xv);
  }
  *reinterpret_cast<short8*>(act + pa) = o;
}

// ---------------- projection (reads ACT16) --------------------------------
__global__ __launch_bounds__(256) void proj_kernel(
    const unsigned short* __restrict__ act, const float* __restrict__ w,
    const float* __restrict__ b, float* __restrict__ out) {
  int v = blockIdx.x * 256 + threadIdx.x;
  int z = v % 12, y = (v / 12) % 24, xx = (v / 288) % 24, t = v / 6912;
  size_t pa = ((size_t)((t * 24 + xx) * 28 + y + 2) * 16 + z + 2) * 16;
  const short8* p = reinterpret_cast<const short8*>(act + pa);
  short8 a0 = p[0], a1 = p[1];
  float s = b[0];
  #pragma unroll
  for (int k = 0; k < 8; ++k) s = fmaf(bf2f((unsigned short)a0[k]), w[k], s);
  #pragma unroll
  for (int k = 0; k < 8; ++k) s = fmaf(bf2f((unsigned short)a1[k]), w[8 + k], s);
  out[v] = s;
}

extern "C" void kernel_launch(void* const* d_in, const int* in_sizes, int n_in,
                              void* d_out, int out_size, void* d_ws, size_t ws_size,
                              hipStream_t stream) {
  const float* x      = (const float*)d_in[0];
  const float* w_emb  = (const float*)d_in[1];
  const float* b_emb  = (const float*)d_in[2];
  const float* w1     = (const float*)d_in[3];
  const float* b1     = (const float*)d_in[4];
  const float* g1     = (const float*)d_in[5];
  const float* be1    = (const float*)d_in[6];
  const float* w2     = (const float*)d_in[7];
  const float* b2     = (const float*)d_in[8];
  const float* g2     = (const float*)d_in[9];
  const float* be2    = (const float*)d_in[10];
  const float* w3     = (const float*)d_in[11];
  const float* b3     = (const float*)d_in[12];
  const float* g3     = (const float*)d_in[13];
  const float* be3    = (const float*)d_in[14];
  const float* w_proj = (const float*)d_in[15];
  const float* b_proj = (const float*)d_in[16];

  char* ws = (char*)d_ws;
  unsigned short* ACT16 = (unsigned short*)(ws + ACT16_B);
  unsigned short* ACT32 = (unsigned short*)(ws + ACT32_B);
  unsigned short* CONVB = (unsigned short*)(ws + CONVB_B);
  short8* WB = (short8*)(ws + WB_B);
  float* PART = (float*)(ws + PART_B);
  float* STATS = (float*)(ws + STATS_B);
  float* out = (float*)d_out;

  zero_act<<<ZERO_BLKS, 256, 0, stream>>>((float4*)ws);
  embed_kernel<<<VOL / 256, 256, 0, stream>>>(x, w_emb, b_emb, ACT16);

  // layer 1: 16 -> 16
  wtrans_mfma<16, 16><<<(125 * 3 * 1 * 64 + 255) / 256, 256, 0, stream>>>(w1, WB);
  conv4d_v7<16, 16><<<576, 512, 0, stream>>>(ACT16, WB, b1, CONVB, PART);
  bn_stats2<16><<<1, 256, 0, stream>>>(PART, g1, be1, STATS, 1152);
  bn_apply<16><<<VOL * 16 / 2048, 256, 0, stream>>>(CONVB, STATS, ACT16);

  // layer 2: 16 -> 32
  wtrans_mfma<16, 32><<<(125 * 3 * 2 * 64 + 255) / 256, 256, 0, stream>>>(w2, WB);
  conv4d_v7<16, 32><<<576, 512, 0, stream>>>(ACT16, WB, b2, CONVB, PART);
  bn_stats2<32><<<1, 256, 0, stream>>>(PART, g2, be2, STATS, 1152);
  bn_apply<32><<<VOL * 32 / 2048, 256, 0, stream>>>(CONVB, STATS, ACT32);

  // layer 3: 32 -> 16
  wtrans_mfma<32, 16><<<(125 * 5 * 1 * 64 + 255) / 256, 256, 0, stream>>>(w3, WB);
  conv4d_v7<32, 16><<<576, 512, 0, stream>>>(ACT32, WB, b3, CONVB, PART);
  bn_stats2<16><<<1, 256, 0, stream>>>(PART, g3, be3, STATS, 1152);
  bn_apply<16><<<VOL * 16 / 2048, 256, 0, stream>>>(CONVB, STATS, ACT16);

  proj_kernel<<<VOL / 256, 256, 0, stream>>>(ACT16, w_proj, b_proj, out);
}

// Round 8
// 208.730 us; speedup vs baseline: 1.5801x; 1.0011x over previous
//
#include <hip/hip_runtime.h>

typedef short short8 __attribute__((ext_vector_type(8)));
typedef float floatx4 __attribute__((ext_vector_type(4)));

#define VOL 41472   // 6*24*24*12
#define EPSV 1e-5f
#define SLOPE 0.1f

// Padded act half-tensors (stride 16 ch): pv(t,x,y,z) = ((t*24+x)*28+y+2)*16+z+2
// half h at ACT + h*1032192 elems. Halo rows (py 0,1,26,27 / pz 0,1,14,15) zero.
#define HALFBYTES 2064384u
#define HALFELEMS 1032192u
#define ACT_B     256u
#define CONVB_B   (ACT_B + 2u * HALFBYTES)     // 4129280
#define WB_B      (CONVB_B + 2654208u)         // bf16 conv out VOL*32*2
#define PART_B    (WB_B + 1920000u)            // WB: 120000 short8 = 1.92MB
#define STATS_B   (PART_B + 294912u)

__device__ inline unsigned short f2bf(float f) {
  unsigned u = __builtin_bit_cast(unsigned, f);
  unsigned r = u + 0x7fffu + ((u >> 16) & 1u);
  return (unsigned short)(r >> 16);
}
__device__ inline float bf2f(unsigned short h) {
  unsigned u = ((unsigned)h) << 16;
  return __builtin_bit_cast(float, u);
}

__global__ __launch_bounds__(256) void zero_act(float4* __restrict__ p) {
  p[blockIdx.x * 256 + threadIdx.x] = make_float4(0.f, 0.f, 0.f, 0.f);
}

// ---------------- embed -> ACT half0 (stride 16) --------------------------
__global__ __launch_bounds__(256) void embed_kernel(
    const float* __restrict__ x, const float* __restrict__ w,
    const float* __restrict__ b, unsigned short* __restrict__ act) {
  int v = blockIdx.x * 256 + threadIdx.x;
  const float4* xp = reinterpret_cast<const float4*>(x + (size_t)v * 8);
  float4 x0 = xp[0], x1 = xp[1];
  float xv[8] = {x0.x, x0.y, x0.z, x0.w, x1.x, x1.y, x1.z, x1.w};
  float acc[16];
  #pragma unroll
  for (int h = 0; h < 16; ++h) acc[h] = b[h];
  #pragma unroll
  for (int f = 0; f < 8; ++f)
    #pragma unroll
    for (int h = 0; h < 16; ++h)
      acc[h] = fmaf(xv[f], w[f * 16 + h], acc[h]);
  int z = v % 12, y = (v / 12) % 24, xx = (v / 288) % 24, t = v / 6912;
  size_t pa = ((size_t)((t * 24 + xx) * 28 + y + 2) * 16 + z + 2) * 16;
  short8 o0, o1;
  #pragma unroll
  for (int h = 0; h < 8; ++h) { o0[h] = (short)f2bf(acc[h]); o1[h] = (short)f2bf(acc[8 + h]); }
  short8* op = reinterpret_cast<short8*>(act + pa);
  op[0] = o0; op[1] = o1;
}

// ---------------- all weights -> B-frag bf16, one dispatch ----------------
// Region L1: ids [0,24000): ((q*3+p))*64+lane, CIN16 COUT16
// Region L2: ids [24000,72000): ((q*3+p)*2+cg)*64+lane, CIN16 COUT32
// Region L3: ids [72000,120000): ((Q*3+p))*64+lane, Q=q125*2+h, ci-halves of 32
__global__ __launch_bounds__(256) void wtrans_all(
    const float* __restrict__ w1, const float* __restrict__ w2,
    const float* __restrict__ w3, short8* __restrict__ wb) {
  int id = blockIdx.x * 256 + threadIdx.x;
  if (id >= 120000) return;
  int lane = id & 63;
  int n = lane & 15, g = lane >> 4;
  int dzb = g >> 1, cib = (g & 1) * 8;
  short8 out;
  if (id < 24000) {
    int q6 = id >> 6;
    int p = q6 % 3, q = q6 / 3;
    int dz = 2 * p + dzb;
    #pragma unroll
    for (int j = 0; j < 8; ++j)
      out[j] = (short)((dz < 5) ? f2bf(w1[((size_t)n * 16 + cib + j) * 625 + q * 5 + dz]) : 0);
  } else if (id < 72000) {
    int q6 = (id - 24000) >> 6;
    int cg = q6 & 1, p = (q6 >> 1) % 3, q = q6 / 6;
    int dz = 2 * p + dzb;
    int co = cg * 16 + n;
    #pragma unroll
    for (int j = 0; j < 8; ++j)
      out[j] = (short)((dz < 5) ? f2bf(w2[((size_t)co * 16 + cib + j) * 625 + q * 5 + dz]) : 0);
  } else {
    int q6 = (id - 72000) >> 6;
    int p = q6 % 3, Q = q6 / 3;
    int h = Q & 1, q125 = Q >> 1;
    int dz = 2 * p + dzb;
    #pragma unroll
    for (int j = 0; j < 8; ++j)
      out[j] = (short)((dz < 5) ? f2bf(w3[((size_t)n * 32 + h * 16 + cib + j) * 625 + q125 * 5 + dz]) : 0);
  }
  wb[id] = out;
}

// ---------------- conv4d v8: unified CIN-eff16, dbuf, 1 barrier/step ------
// 576 blocks (t,x,yq=6rows) x 8 waves (2 y-triples x 4 vtap-slices), 512 thr.
// vtaps = valid(dt,dx) x NH ci-halves. Per vtap: stage 10py x 16pz x 16ch slab
// (48B padded rows) double-buffered; A via ds_read_b128 imm offsets, rolling
// 3-row window; epilogue LDS-reduces 4 slices + bias + bf16 + BN partials.
template<int NH, int NCOG>
__global__ __launch_bounds__(512, 4) void conv4d_v8(
    const unsigned short* __restrict__ act, const short8* __restrict__ wb,
    const float* __restrict__ bias, unsigned short* __restrict__ convout,
    float* __restrict__ part) {
  constexpr int NP = 3;
  constexpr int COUT = NCOG * 16;
  constexpr int RSP = 48;                   // padded LDS row stride (32B data)
  constexpr int BUFSZ = 165 * RSP;          // 2 guard + 160 data + 3 guard rows
  constexpr int DYST = NH * NP * NCOG * 64; // short8 units per dy step

  __shared__ __align__(16) char lds[8 * BUFSZ];
  __shared__ int vlist[52];

  const int tid = threadIdx.x;
  const int l = tid & 63;
  const int w = tid >> 6;
  const int ks = w & 3;
  const int yt = w >> 2;
  const int col = l & 15, g = l >> 4;
  const int bid = blockIdx.x;
  const int yq = bid & 3;
  const int x = (bid >> 2) % 24;
  const int t = bid / 96;
  const int y0q = yq * 6;

  // zero guard rows (0,1,162,163,164) of all 8 buffers
  for (int i = tid; i < 8 * 60; i += 512) {
    int b = i / 60, k = i % 60;
    int row_sel = k / 12, word = k % 12;
    int row = (row_sel < 2) ? row_sel : (row_sel + 160);
    ((int*)(lds + b * BUFSZ))[row * 12 + word] = 0;
  }
  if (tid == 0) {
    int n = 0;
    for (int dt = 0; dt < 5; ++dt) {
      int ti = t + dt - 2;
      if ((unsigned)ti >= 6u) continue;
      for (int dx = 0; dx < 5; ++dx) {
        int xi = x + dx - 2;
        if ((unsigned)xi >= 24u) continue;
        int pi = ti * 24 + xi;
        int txq = dt * 5 + dx;
        for (int h = 0; h < NH; ++h)
          vlist[n++] = (pi << 16) | (txq * 5 * NH + h);
      }
    }
    vlist[51] = n;
  }
  __syncthreads();
  const int nv = vlist[51];
  const int lo = (nv * ks) >> 2;
  const int hi = (nv * (ks + 1)) >> 2;
  const int nsteps = (nv + 3) >> 2;

  char* const buf0 = lds + (ks * 2) * BUFSZ;
  char* const buf1 = lds + (ks * 2 + 1) * BUFSZ;
  const int sid = yt * 64 + l;               // staging id 0..127
  const bool r2v = (sid < 64);               // chunk sid+256 < 320
  const char* const abase = (const char*)act;

  // A-frag ds_read bases (guard offset +2 rows and pz offset -2 cancel)
  const char* const arp0 = buf0 + (yt * 48 + col + (g >> 1)) * RSP + (g & 1) * 16;
  const char* const arp1 = buf1 + (yt * 48 + col + (g >> 1)) * RSP + (g & 1) * 16;

  floatx4 acc[3][NCOG];
  #pragma unroll
  for (int m = 0; m < 3; ++m)
    #pragma unroll
    for (int cg = 0; cg < NCOG; ++cg) acc[m][cg] = (floatx4){0.f, 0.f, 0.f, 0.f};

  short8 R[3];
  // prologue: load+store vtap lo into buf0; issue loads for vtap lo+1
  if (lo < hi) {
    int e = vlist[lo];
    int pi = e >> 16, h = (NH == 2) ? (e & 1) : 0;
    const char* src = abase + (size_t)h * HALFBYTES +
        ((size_t)(pi * 28 + y0q) * 16) * 32 + (sid >> 1) * 32 + (sid & 1) * 16;
    R[0] = *(const short8*)(src);
    R[1] = *(const short8*)(src + 2048);
    if (r2v) R[2] = *(const short8*)(src + 4096);
    char* d = buf0 + 96 + (sid >> 1) * 48 + (sid & 1) * 16;
    *(short8*)(d) = R[0];
    *(short8*)(d + 3072) = R[1];
    if (r2v) *(short8*)(d + 6144) = R[2];
  }
  if (lo + 1 < hi) {
    int e = vlist[lo + 1];
    int pi = e >> 16, h = (NH == 2) ? (e & 1) : 0;
    const char* src = abase + (size_t)h * HALFBYTES +
        ((size_t)(pi * 28 + y0q) * 16) * 32 + (sid >> 1) * 32 + (sid & 1) * 16;
    R[0] = *(const short8*)(src);
    R[1] = *(const short8*)(src + 2048);
    if (r2v) R[2] = *(const short8*)(src + 4096);
  }

  for (int s = 0; s < nsteps; ++s) {
    __syncthreads();                         // buf[s&1] staged & prior reads done
    // write next vtap's slab into the other buffer (loaded last step)
    if (lo + s + 1 < hi) {
      char* d = ((s & 1) ? buf0 : buf1) + 96 + (sid >> 1) * 48 + (sid & 1) * 16;
      *(short8*)(d) = R[0];
      *(short8*)(d + 3072) = R[1];
      if (r2v) *(short8*)(d + 6144) = R[2];
    }
    // issue global loads for vtap s+2
    if (lo + s + 2 < hi) {
      int e = vlist[lo + s + 2];
      int pi = e >> 16, h = (NH == 2) ? (e & 1) : 0;
      const char* src = abase + (size_t)h * HALFBYTES +
          ((size_t)(pi * 28 + y0q) * 16) * 32 + (sid >> 1) * 32 + (sid & 1) * 16;
      R[0] = *(const short8*)(src);
      R[1] = *(const short8*)(src + 2048);
      if (r2v) R[2] = *(const short8*)(src + 4096);
    }
    // compute current vtap
    if (lo + s < hi) {
      const int e = vlist[lo + s];
      const short8* bp = wb + (size_t)(e & 0xFFFF) * (NP * NCOG * 64) + l;
      const char* arp = (s & 1) ? arp1 : arp0;
      short8 W[3][3];
      #pragma unroll
      for (int r = 0; r < 3; ++r)
        #pragma unroll
        for (int p = 0; p < 3; ++p)
          W[r][p] = *(const short8*)(arp + r * 768 + p * 96);
      #pragma unroll
      for (int dy = 0; dy < 5; ++dy) {
        short8 Bf[3][NCOG];
        #pragma unroll
        for (int p = 0; p < 3; ++p)
          #pragma unroll
          for (int cg = 0; cg < NCOG; ++cg)
            Bf[p][cg] = bp[dy * DYST + (p * NCOG + cg) * 64];
        #pragma unroll
        for (int p = 0; p < 3; ++p)
          #pragma unroll
          for (int cg = 0; cg < NCOG; ++cg)
            #pragma unroll
            for (int m = 0; m < 3; ++m)
              acc[m][cg] = __builtin_amdgcn_mfma_f32_16x16x32_bf16(
                  W[(dy + m) % 3][p], Bf[p][cg], acc[m][cg], 0, 0, 0);
        if (dy < 4) {
          #pragma unroll
          for (int p = 0; p < 3; ++p)
            W[dy % 3][p] = *(const short8*)(arp + (dy + 3) * 768 + p * 96);
        }
      }
    }
  }

  // ---- epilogue: reduce 4 slices (LDS overlay), bias, bf16, BN partials ----
  float4* redf = (float4*)lds;
  const int nred = 2 * NCOG;
  const int ryt = (NCOG == 2) ? (w >> 1) : w;
  const int rcg = (NCOG == 2) ? (w & 1) : 0;
  const bool isred = w < nred;
  const float bvv = isred ? bias[rcg * 16 + col] : 0.f;
  float rs1 = 0.f, rs2 = 0.f;
  #pragma unroll
  for (int m = 0; m < 3; ++m) {
    __syncthreads();
    #pragma unroll
    for (int cg = 0; cg < NCOG; ++cg) {
      floatx4 a = acc[m][cg];
      redf[(w * NCOG + cg) * 64 + l] = make_float4(a[0], a[1], a[2], a[3]);
    }
    __syncthreads();
    if (isred) {
      float vs[4] = {0.f, 0.f, 0.f, 0.f};
      #pragma unroll
      for (int k = 0; k < 4; ++k) {
        float4 vv = redf[((ryt * 4 + k) * NCOG + rcg) * 64 + l];
        vs[0] += vv.x; vs[1] += vv.y; vs[2] += vv.z; vs[3] += vv.w;
      }
      const int yy = y0q + ryt * 3 + m;
      const int vbase = ((t * 24 + x) * 24 + yy) * 12;
      #pragma unroll
      for (int i = 0; i < 4; ++i) {
        int pz = g * 4 + i;
        float val = vs[i] + bvv;
        if ((unsigned)(pz - 2) < 12u) {
          convout[(size_t)(vbase + pz - 2) * COUT + rcg * 16 + col] = f2bf(val);
          rs1 += val;
          rs2 = fmaf(val, val, rs2);
        }
      }
    }
  }
  if (isred) {
    rs1 += __shfl_xor(rs1, 16); rs1 += __shfl_xor(rs1, 32);
    rs2 += __shfl_xor(rs2, 16); rs2 += __shfl_xor(rs2, 32);
    if (l < 16) {
      size_t pb = ((size_t)(bid * 2 + ryt) * COUT + rcg * 16 + l) * 2;
      part[pb] = rs1; part[pb + 1] = rs2;
    }
  }
}

// ---------------- BN stats: reduce 1152 block-partials --------------------
template<int C>
__global__ __launch_bounds__(256) void bn_stats2(
    const float* __restrict__ part, const float* __restrict__ gam,
    const float* __restrict__ bet, float* __restrict__ stats) {
  constexpr int NS = 256 / C;
  int tid = threadIdx.x;
  int c = tid & (C - 1);
  int sl = tid / C;
  float S = 0.f, S2 = 0.f;
  for (int b = sl; b < 1152; b += NS) {
    S  += part[((size_t)b * C + c) * 2];
    S2 += part[((size_t)b * C + c) * 2 + 1];
  }
  __shared__ float sh[256][2];
  sh[tid][0] = S; sh[tid][1] = S2;
  __syncthreads();
  if (tid < C) {
    float s = 0.f, s2 = 0.f;
    #pragma unroll
    for (int k = 0; k < NS; ++k) { s += sh[k * C + tid][0]; s2 += sh[k * C + tid][1]; }
    float mean = s * (1.f / VOL);
    float var = s2 * (1.f / VOL) - mean * mean;
    float sc = gam[tid] * rsqrtf(var + EPSV);
    stats[2 * tid] = sc;
    stats[2 * tid + 1] = fmaf(-mean, sc, bet[tid]);
  }
}

// ---------------- BN apply + LeakyReLU -> padded bf16 act halves ----------
template<int C>
__global__ __launch_bounds__(256) void bn_apply(
    const unsigned short* __restrict__ convb, const float* __restrict__ stats,
    unsigned short* __restrict__ act) {
  int i = blockIdx.x * 256 + threadIdx.x;     // covers VOL*C/8
  size_t e = (size_t)i * 8;
  int v = (int)(e / C);
  int cb = (int)(e & (C - 1));
  int z = v % 12, y = (v / 12) % 24, xx = (v / 288) % 24, t = v / 6912;
  size_t pv = (size_t)((t * 24 + xx) * 28 + y + 2) * 16 + z + 2;
  size_t pa = (C == 16) ? (pv * 16 + cb)
                        : ((size_t)(cb >> 4) * HALFELEMS + pv * 16 + (cb & 15));
  short8 in = *reinterpret_cast<const short8*>(convb + e);
  short8 o;
  #pragma unroll
  for (int k = 0; k < 8; ++k) {
    float sc = stats[2 * (cb + k)], sh = stats[2 * (cb + k) + 1];
    float xv = fmaf(bf2f((unsigned short)in[k]), sc, sh);
    xv = fmaxf(xv, SLOPE * xv);
    o[k] = (short)f2bf(xv);
  }
  *reinterpret_cast<short8*>(act + pa) = o;
}

// ---------------- layer3 BN apply + LeakyReLU + projection (fused) --------
__global__ __launch_bounds__(256) void bn_apply_proj(
    const unsigned short* __restrict__ convb, const float* __restrict__ stats,
    const float* __restrict__ wp, const float* __restrict__ bpj,
    float* __restrict__ out) {
  int i = blockIdx.x * 256 + threadIdx.x;     // 2 threads per voxel
  int v = i >> 1;
  int cb = (i & 1) * 8;
  short8 in = *reinterpret_cast<const short8*>(convb + (size_t)v * 16 + cb);
  float s = 0.f;
  #pragma unroll
  for (int k = 0; k < 8; ++k) {
    float sc = stats[2 * (cb + k)], sh = stats[2 * (cb + k) + 1];
    float xv = fmaf(bf2f((unsigned short)in[k]), sc, sh);
    xv = fmaxf(xv, SLOPE * xv);
    s = fmaf(xv, wp[cb + k], s);
  }
  float o = s + __shfl_xor(s, 1);
  if ((i & 1) == 0) out[v] = o + bpj[0];
}

extern "C" void kernel_launch(void* const* d_in, const int* in_sizes, int n_in,
                              void* d_out, int out_size, void* d_ws, size_t ws_size,
                              hipStream_t stream) {
  const float* x      = (const float*)d_in[0];
  const float* w_emb  = (const float*)d_in[1];
  const float* b_emb  = (const float*)d_in[2];
  const float* w1     = (const float*)d_in[3];
  const float* b1     = (const float*)d_in[4];
  const float* g1     = (const float*)d_in[5];
  const float* be1    = (const float*)d_in[6];
  const float* w2     = (const float*)d_in[7];
  const float* b2     = (const float*)d_in[8];
  const float* g2     = (const float*)d_in[9];
  const float* be2    = (const float*)d_in[10];
  const float* w3     = (const float*)d_in[11];
  const float* b3     = (const float*)d_in[12];
  const float* g3     = (const float*)d_in[13];
  const float* be3    = (const float*)d_in[14];
  const float* w_proj = (const float*)d_in[15];
  const float* b_proj = (const float*)d_in[16];

  char* ws = (char*)d_ws;
  unsigned short* ACT   = (unsigned short*)(ws + ACT_B);
  unsigned short* CONVB = (unsigned short*)(ws + CONVB_B);
  short8* WB            = (short8*)(ws + WB_B);
  float* PART           = (float*)(ws + PART_B);
  float* STATS          = (float*)(ws + STATS_B);
  float* out            = (float*)d_out;

  zero_act<<<1009, 256, 0, stream>>>((float4*)ws);   // ACT halves + halo
  embed_kernel<<<VOL / 256, 256, 0, stream>>>(x, w_emb, b_emb, ACT);
  wtrans_all<<<469, 256, 0, stream>>>(w1, w2, w3, WB);

  // layer 1: 16 -> 16
  conv4d_v8<1, 1><<<576, 512, 0, stream>>>(ACT, WB, b1, CONVB, PART);
  bn_stats2<16><<<1, 256, 0, stream>>>(PART, g1, be1, STATS);
  bn_apply<16><<<324, 256, 0, stream>>>(CONVB, STATS, ACT);

  // layer 2: 16 -> 32 (writes two ci-half tensors)
  conv4d_v8<1, 2><<<576, 512, 0, stream>>>(ACT, WB + 24000, b2, CONVB, PART);
  bn_stats2<32><<<1, 256, 0, stream>>>(PART, g2, be2, STATS);
  bn_apply<32><<<648, 256, 0, stream>>>(CONVB, STATS, ACT);

  // layer 3: 32 -> 16 (NH=2 ci-half vtaps), fused BN+proj epilogue
  conv4d_v8<2, 1><<<576, 512, 0, stream>>>(ACT, WB + 72000, b3, CONVB, PART);
  bn_stats2<16><<<1, 256, 0, stream>>>(PART, g3, be3, STATS);
  bn_apply_proj<<<324, 256, 0, stream>>>(CONVB, STATS, w_proj, b_proj, out);
}